// Round 7
// baseline (11.629 us; speedup 1.0000x reference)
//
#include <hip/hip_runtime.h>

#define NP 1048576
#define BLOCK 256
#define PPT 8
#define NBLK (NP / (BLOCK * PPT))   /* 512 */
#define W_IN 0.001f
#define W_OUT 1.0f
#define TOL 1e-8f
#define SQRT3 1.7320508f

// ws float layout:
//   [0,512)     per-block S      [512,1024) per-block C     [1024,1536) per-block M
//   L1 counters (64): u32 @ 1536 + 16*g1          (g1 = bid & 63, 8 blocks/group)
//   L1 aggregates:    S1 @ 2560+g1, C1 @ 2624+g1, M1 @ 2688+g1
//   L2 counters (8):  u32 @ 2816 + 16*g2          (g2 = g1 & 7, 8 winners/group)
//   L2 aggregates:    S2 @ 3072+g2, C2 @ 3080+g2, M2 @ 3088+g2
//   L3 counter:       u32 @ 3104                   (8 increments)
// All cross-block ops relaxed agent-scope (coherence-point direct, no cache
// maintenance); producer ordering via s_waitcnt vmcnt(0). Counter tests use
// (ret & 7)==7 -> correct for any initial (poisoned/leftover) counter value.

__device__ __forceinline__ void drain_vmem() {
    asm volatile("s_waitcnt vmcnt(0)" ::: "memory");
}
__device__ __forceinline__ void st(float* p, float v) {
    __hip_atomic_store(p, v, __ATOMIC_RELAXED, __HIP_MEMORY_SCOPE_AGENT);
}
__device__ __forceinline__ float ld(const float* p) {
    return __hip_atomic_load(p, __ATOMIC_RELAXED, __HIP_MEMORY_SCOPE_AGENT);
}
__device__ __forceinline__ unsigned bump(unsigned* p) {
    return __hip_atomic_fetch_add(p, 1u, __ATOMIC_RELAXED, __HIP_MEMORY_SCOPE_AGENT);
}

__global__ __launch_bounds__(BLOCK) void pbl_fused(
    const float* __restrict__ pts, float* __restrict__ ws, float* __restrict__ out)
{
    __shared__ float s_s[BLOCK/64], s_c[BLOCK/64], s_m[BLOCK/64];
    __shared__ int s_last;

    const int lt = threadIdx.x;
    const int tid = blockIdx.x * BLOCK + lt;
    const float4* p4 = (const float4*)pts;
    float4 f[6];
    #pragma unroll
    for (int k = 0; k < 6; ++k) f[k] = p4[tid*6 + k];
    float px[PPT] = {f[0].x, f[0].w, f[1].z, f[2].y, f[3].x, f[3].w, f[4].z, f[5].y};
    float py[PPT] = {f[0].y, f[1].x, f[1].w, f[2].z, f[3].y, f[4].x, f[4].w, f[5].z};
    float pz[PPT] = {f[0].z, f[1].y, f[2].x, f[2].w, f[3].z, f[4].y, f[5].x, f[5].w};

    float sum_in = 0.f, cnt_in = 0.f, mx_out = 0.f;
    #pragma unroll
    for (int i = 0; i < PPT; ++i) {
        float ux = fabsf(px[i]), uy = fabsf(py[i]), uz = fabsf(pz[i]);
        float s1 = ux + uy + uz;
        float hi = fmaxf(ux, fmaxf(uy, uz));
        float lo = fminf(ux, fminf(uy, uz));
        float mid = s1 - hi - lo;
        float ss = fmaf(px[i], px[i], fmaf(py[i], py[i], pz[i]*pz[i]));

        bool inside = (s1 - 1.f) <= TOL * SQRT3;           // max plane violation
        float d2v = fmaf(-2.f, hi, ss) + 1.f;              // min d2 to +-e_i vertices

        float t3 = (s1 - 1.f) * (1.f/3.f);                 // simplex projection
        float t2 = (hi + mid - 1.f) * 0.5f;
        float t1 = hi - 1.f;
        float d2_3 = 3.f * t3 * t3;
        float d2_2 = fmaf(lo, lo, 2.f * t2 * t2);
        float d2_1 = fmaf(t1, t1, fmaf(mid, mid, lo * lo));
        float sq = (lo > t3) ? d2_3 : ((mid > t2) ? d2_2 : d2_1);

        sum_in += inside ? d2v : 0.f;
        cnt_in += inside ? 1.f : 0.f;
        mx_out  = inside ? mx_out : fmaxf(mx_out, sq);
    }

    #pragma unroll
    for (int o = 32; o > 0; o >>= 1) {
        sum_in += __shfl_down(sum_in, o);
        cnt_in += __shfl_down(cnt_in, o);
        mx_out  = fmaxf(mx_out, __shfl_down(mx_out, o));
    }
    const int wave = lt >> 6;
    if ((lt & 63) == 0) { s_s[wave] = sum_in; s_c[wave] = cnt_in; s_m[wave] = mx_out; }
    __syncthreads();

    unsigned* wsu = (unsigned*)ws;
    const int g1 = blockIdx.x & 63;
    const int g2 = g1 & 7;

    if (lt == 0) {
        float S = 0.f, C = 0.f, M = 0.f;
        #pragma unroll
        for (int i = 0; i < BLOCK/64; ++i) { S += s_s[i]; C += s_c[i]; M = fmaxf(M, s_m[i]); }
        st(&ws[blockIdx.x], S);
        st(&ws[512 + blockIdx.x], C);
        st(&ws[1024 + blockIdx.x], M);
        drain_vmem();
        unsigned ret = bump(&wsu[1536 + 16*g1]);
        s_last = ((ret & 7) == 7) ? 1 : 0;
    }
    __syncthreads();

    if (s_last && lt < 64) {
        const int lane = lt;
        // L1 winner: reduce 8 block-partials of group g1 (blocks g1 + 64j)
        float S = 0.f, C = 0.f, M = 0.f;
        if (lane < 8) {
            int b = g1 + (lane << 6);
            S = ld(&ws[b]); C = ld(&ws[512 + b]); M = ld(&ws[1024 + b]);
        }
        #pragma unroll
        for (int o = 4; o > 0; o >>= 1) {
            S += __shfl_down(S, o);
            C += __shfl_down(C, o);
            M  = fmaxf(M, __shfl_down(M, o));
        }
        int last2 = 0;
        if (lane == 0) {
            st(&ws[2560 + g1], S); st(&ws[2624 + g1], C); st(&ws[2688 + g1], M);
            drain_vmem();
            unsigned r2 = bump(&wsu[2816 + 16*g2]);
            last2 = ((r2 & 7) == 7) ? 1 : 0;
        }
        last2 = __shfl(last2, 0);
        if (last2) {
            // L2 winner: reduce 8 L1 aggregates of group g2 (g1' = g2 + 8k)
            float S2 = 0.f, C2 = 0.f, M2 = 0.f;
            if (lane < 8) {
                int gg = g2 + (lane << 3);
                S2 = ld(&ws[2560 + gg]); C2 = ld(&ws[2624 + gg]); M2 = ld(&ws[2688 + gg]);
            }
            #pragma unroll
            for (int o = 4; o > 0; o >>= 1) {
                S2 += __shfl_down(S2, o);
                C2 += __shfl_down(C2, o);
                M2  = fmaxf(M2, __shfl_down(M2, o));
            }
            int last3 = 0;
            if (lane == 0) {
                st(&ws[3072 + g2], S2); st(&ws[3080 + g2], C2); st(&ws[3088 + g2], M2);
                drain_vmem();
                unsigned r3 = bump(&wsu[3104]);
                last3 = ((r3 & 7) == 7) ? 1 : 0;
            }
            last3 = __shfl(last3, 0);
            if (last3) {
                // L3 winner: reduce the 8 L2 aggregates, write result
                float S3 = 0.f, C3 = 0.f, M3 = 0.f;
                if (lane < 8) {
                    S3 = ld(&ws[3072 + lane]); C3 = ld(&ws[3080 + lane]); M3 = ld(&ws[3088 + lane]);
                }
                #pragma unroll
                for (int o = 4; o > 0; o >>= 1) {
                    S3 += __shfl_down(S3, o);
                    C3 += __shfl_down(C3, o);
                    M3  = fmaxf(M3, __shfl_down(M3, o));
                }
                if (lane == 0) {
                    float li = (C3 > 0.f) ? W_IN * S3 / C3 : 0.f;
                    float nout = (float)NP - C3;
                    float lo = (nout > 0.f) ? W_OUT * M3 : 0.f;
                    out[0] = li + lo;
                }
            }
        }
    }
}

extern "C" void kernel_launch(void* const* d_in, const int* in_sizes, int n_in,
                              void* d_out, int out_size, void* d_ws, size_t ws_size,
                              hipStream_t stream) {
    const float* pts = (const float*)d_in[0];
    float* ws = (float*)d_ws;
    float* out = (float*)d_out;
    pbl_fused<<<NBLK, BLOCK, 0, stream>>>(pts, ws, out);
}

// Round 8
// 10.705 us; speedup vs baseline: 1.0863x; 1.0863x over previous
//
#include <hip/hip_runtime.h>

#define NP 1048576
#define BLOCK 256
#define PPT 4
#define NBLK (NP / (BLOCK * PPT))   /* 1024 */
#define GROUPS 32
#define GSIZE (NBLK / GROUPS)       /* 32 */
#define W_IN 0.001f
#define W_OUT 1.0f
#define TOL 1e-8f
#define SQRT3 1.7320508f

// ws float layout:
//   [0,1024)      per-block S
//   [1024,2048)   per-block C
//   [2048,3072)   per-block M
//   u32 counters level-1 at 3072 + g*16   (64B apart, g<32)
//   group aggregates: S_g at 3584+g, C_g at 3616+g, M_g at 3648+g
//   u32 counter level-2 at 3712
// All cross-block traffic: RELAXED agent-scope atomics (coherence-point
// direct, no per-op cache maintenance) + s_waitcnt vmcnt(0) producer drains.
// Counter winner tests use (ret & N-1)==N-1 -> poison/leftover-safe.

__device__ __forceinline__ void drain_vmem() {
    asm volatile("s_waitcnt vmcnt(0)" ::: "memory");
}
__device__ __forceinline__ void st(float* p, float v) {
    __hip_atomic_store(p, v, __ATOMIC_RELAXED, __HIP_MEMORY_SCOPE_AGENT);
}
__device__ __forceinline__ float ld(const float* p) {
    return __hip_atomic_load(p, __ATOMIC_RELAXED, __HIP_MEMORY_SCOPE_AGENT);
}
__device__ __forceinline__ unsigned bump(unsigned* p) {
    return __hip_atomic_fetch_add(p, 1u, __ATOMIC_RELAXED, __HIP_MEMORY_SCOPE_AGENT);
}

__global__ __launch_bounds__(BLOCK) void pbl_fused(
    const float* __restrict__ pts, float* __restrict__ ws, float* __restrict__ out)
{
    __shared__ float s_s[BLOCK/64], s_c[BLOCK/64], s_m[BLOCK/64];

    const int lt = threadIdx.x;
    const int tid = blockIdx.x * BLOCK + lt;
    const float4* p4 = (const float4*)pts;
    float4 f0 = p4[tid*3+0];
    float4 f1 = p4[tid*3+1];
    float4 f2 = p4[tid*3+2];
    float px[PPT] = {f0.x, f0.w, f1.z, f2.y};
    float py[PPT] = {f0.y, f1.x, f1.w, f2.z};
    float pz[PPT] = {f0.z, f1.y, f2.x, f2.w};

    float sum_in = 0.f, mx_out = 0.f;
    bool ins[PPT];
    #pragma unroll
    for (int i = 0; i < PPT; ++i) {
        float ux = fabsf(px[i]), uy = fabsf(py[i]), uz = fabsf(pz[i]);
        float s1 = ux + uy + uz;
        float hi = fmaxf(ux, fmaxf(uy, uz));
        float lo = fminf(ux, fminf(uy, uz));
        float mid = s1 - hi - lo;
        float ss = fmaf(px[i], px[i], fmaf(py[i], py[i], pz[i]*pz[i]));

        bool inside = (s1 - 1.f) <= TOL * SQRT3;           // max plane violation
        float d2v = fmaf(-2.f, hi, ss) + 1.f;              // min d2 to +-e_i vertices

        float t3 = (s1 - 1.f) * (1.f/3.f);                 // simplex projection
        float t2 = (hi + mid - 1.f) * 0.5f;
        float t1 = hi - 1.f;
        float d2_3 = 3.f * t3 * t3;
        float d2_2 = fmaf(lo, lo, 2.f * t2 * t2);
        float d2_1 = fmaf(t1, t1, fmaf(mid, mid, lo * lo));
        float sq = (lo > t3) ? d2_3 : ((mid > t2) ? d2_2 : d2_1);

        ins[i] = inside;
        sum_in += inside ? d2v : 0.f;
        mx_out  = inside ? mx_out : fmaxf(mx_out, sq);
    }

    // inside-count via ballot (scalar pipe) -- no shuffle chain needed
    int wcnt = 0;
    #pragma unroll
    for (int i = 0; i < PPT; ++i)
        wcnt += __popcll(__ballot(ins[i]));

    // wave reduce sum & max (2 chains x 6 rounds)
    #pragma unroll
    for (int o = 32; o > 0; o >>= 1) {
        sum_in += __shfl_down(sum_in, o);
        mx_out  = fmaxf(mx_out, __shfl_down(mx_out, o));
    }
    const int wave = lt >> 6;
    if ((lt & 63) == 0) { s_s[wave] = sum_in; s_c[wave] = (float)wcnt; s_m[wave] = mx_out; }
    __syncthreads();

    if (lt < 64) {                       // wave 0 runs the entire tail
        unsigned* wsu = (unsigned*)ws;
        const int g = blockIdx.x & (GROUPS - 1);

        float S = 0.f, C = 0.f, M = 0.f;
        if (lt < BLOCK/64) { S = s_s[lt]; C = s_c[lt]; M = s_m[lt]; }
        S += __shfl_down(S, 2); C += __shfl_down(C, 2); M = fmaxf(M, __shfl_down(M, 2));
        S += __shfl_down(S, 1); C += __shfl_down(C, 1); M = fmaxf(M, __shfl_down(M, 1));

        unsigned ret = 0;
        if (lt == 0) {
            st(&ws[blockIdx.x],          S);
            st(&ws[NBLK + blockIdx.x],   C);
            st(&ws[2*NBLK + blockIdx.x], M);
            drain_vmem();                 // partials acked before increment
            ret = bump(&wsu[3*NBLK + (g << 4)]);
        }
        ret = __shfl(ret, 0);             // in-wave broadcast, no barrier

        if ((ret & (GSIZE - 1)) == (GSIZE - 1)) {
            // L1 winner: reduce this group's 32 block-partials
            float S1 = 0.f, C1 = 0.f, M1 = 0.f;
            if (lt < GSIZE) {
                int b = g + (lt << 5);    // blocks with bid % 32 == g
                S1 = ld(&ws[b]); C1 = ld(&ws[NBLK + b]); M1 = ld(&ws[2*NBLK + b]);
            }
            #pragma unroll
            for (int o = 16; o > 0; o >>= 1) {
                S1 += __shfl_down(S1, o);
                C1 += __shfl_down(C1, o);
                M1  = fmaxf(M1, __shfl_down(M1, o));
            }
            unsigned r2 = 0;
            if (lt == 0) {
                st(&ws[3584 + g], S1); st(&ws[3616 + g], C1); st(&ws[3648 + g], M1);
                drain_vmem();
                r2 = bump(&wsu[3712]);
            }
            r2 = __shfl(r2, 0);
            if ((r2 & (GROUPS - 1)) == (GROUPS - 1)) {
                // L2 winner: reduce the 32 group aggregates, write result
                float S2 = 0.f, C2 = 0.f, M2 = 0.f;
                if (lt < GROUPS) {
                    S2 = ld(&ws[3584 + lt]); C2 = ld(&ws[3616 + lt]); M2 = ld(&ws[3648 + lt]);
                }
                #pragma unroll
                for (int o = 16; o > 0; o >>= 1) {
                    S2 += __shfl_down(S2, o);
                    C2 += __shfl_down(C2, o);
                    M2  = fmaxf(M2, __shfl_down(M2, o));
                }
                if (lt == 0) {
                    float li = (C2 > 0.f) ? W_IN * S2 / C2 : 0.f;
                    float nout = (float)NP - C2;
                    float lo = (nout > 0.f) ? W_OUT * M2 : 0.f;
                    out[0] = li + lo;
                }
            }
        }
    }
}

extern "C" void kernel_launch(void* const* d_in, const int* in_sizes, int n_in,
                              void* d_out, int out_size, void* d_ws, size_t ws_size,
                              hipStream_t stream) {
    const float* pts = (const float*)d_in[0];
    float* ws = (float*)d_ws;
    float* out = (float*)d_out;
    pbl_fused<<<NBLK, BLOCK, 0, stream>>>(pts, ws, out);
}

// Round 9
// 9.797 us; speedup vs baseline: 1.1870x; 1.0927x over previous
//
#include <hip/hip_runtime.h>

#define NP 1048576
#define BLOCK 256
#define PPT 4
#define NBLK (NP / (BLOCK * PPT))   /* 1024 */
#define GROUPS 32
#define GSIZE (NBLK / GROUPS)       /* 32 */
#define W_IN 0.001f
#define W_OUT 1.0f
#define TOL 1e-8f
#define SQRT3 1.7320508f

// ws float layout:
//   [0,1024)      per-block S
//   [1024,2048)   per-block C
//   [2048,3072)   per-block M
//   L1 counters (32): u32 @ 3072 + 16*g   (64B apart, g = bid & 31)
//   L2 counter:       u32 @ 3584
// Protocol: partial stores (relaxed agent-scope, coherence-point direct) ->
// s_waitcnt vmcnt(0) drain -> bump L1[g]. The 32nd finisher of a group bumps
// L2 directly (no data produced => no drain; ordering via control dependence
// on the returned L1 count). The 32nd L2 bumper reduces all 1024 partials.
// Counter tests use (ret & 31)==31 -> correct for any initial counter value.

__device__ __forceinline__ void drain_vmem() {
    asm volatile("s_waitcnt vmcnt(0)" ::: "memory");
}
__device__ __forceinline__ void st(float* p, float v) {
    __hip_atomic_store(p, v, __ATOMIC_RELAXED, __HIP_MEMORY_SCOPE_AGENT);
}
__device__ __forceinline__ float ld(const float* p) {
    return __hip_atomic_load(p, __ATOMIC_RELAXED, __HIP_MEMORY_SCOPE_AGENT);
}
__device__ __forceinline__ unsigned bump(unsigned* p) {
    return __hip_atomic_fetch_add(p, 1u, __ATOMIC_RELAXED, __HIP_MEMORY_SCOPE_AGENT);
}

__global__ __launch_bounds__(BLOCK) void pbl_fused(
    const float* __restrict__ pts, float* __restrict__ ws, float* __restrict__ out)
{
    __shared__ float s_s[BLOCK/64], s_c[BLOCK/64], s_m[BLOCK/64];

    const int lt = threadIdx.x;
    const int tid = blockIdx.x * BLOCK + lt;
    const float4* p4 = (const float4*)pts;
    float4 f0 = p4[tid*3+0];
    float4 f1 = p4[tid*3+1];
    float4 f2 = p4[tid*3+2];
    float px[PPT] = {f0.x, f0.w, f1.z, f2.y};
    float py[PPT] = {f0.y, f1.x, f1.w, f2.z};
    float pz[PPT] = {f0.z, f1.y, f2.x, f2.w};

    float sum_in = 0.f, mx_out = 0.f;
    bool ins[PPT];
    #pragma unroll
    for (int i = 0; i < PPT; ++i) {
        float ux = fabsf(px[i]), uy = fabsf(py[i]), uz = fabsf(pz[i]);
        float s1 = ux + uy + uz;
        float hi = fmaxf(ux, fmaxf(uy, uz));
        float lo = fminf(ux, fminf(uy, uz));
        float mid = s1 - hi - lo;
        float ss = fmaf(px[i], px[i], fmaf(py[i], py[i], pz[i]*pz[i]));

        bool inside = (s1 - 1.f) <= TOL * SQRT3;           // max plane violation
        float d2v = fmaf(-2.f, hi, ss) + 1.f;              // min d2 to +-e_i vertices

        float t3 = (s1 - 1.f) * (1.f/3.f);                 // simplex projection
        float t2 = (hi + mid - 1.f) * 0.5f;
        float t1 = hi - 1.f;
        float d2_3 = 3.f * t3 * t3;
        float d2_2 = fmaf(lo, lo, 2.f * t2 * t2);
        float d2_1 = fmaf(t1, t1, fmaf(mid, mid, lo * lo));
        float sq = (lo > t3) ? d2_3 : ((mid > t2) ? d2_2 : d2_1);

        ins[i] = inside;
        sum_in += inside ? d2v : 0.f;
        mx_out  = inside ? mx_out : fmaxf(mx_out, sq);
    }

    // inside-count via ballot (scalar pipe) -- no shuffle chain needed
    int wcnt = 0;
    #pragma unroll
    for (int i = 0; i < PPT; ++i)
        wcnt += __popcll(__ballot(ins[i]));

    // wave reduce sum & max
    #pragma unroll
    for (int o = 32; o > 0; o >>= 1) {
        sum_in += __shfl_down(sum_in, o);
        mx_out  = fmaxf(mx_out, __shfl_down(mx_out, o));
    }
    const int wave = lt >> 6;
    if ((lt & 63) == 0) { s_s[wave] = sum_in; s_c[wave] = (float)wcnt; s_m[wave] = mx_out; }
    __syncthreads();

    if (lt < 64) {                       // wave 0 runs the entire tail
        unsigned* wsu = (unsigned*)ws;
        const int g = blockIdx.x & (GROUPS - 1);

        float S = 0.f, C = 0.f, M = 0.f;
        if (lt < BLOCK/64) { S = s_s[lt]; C = s_c[lt]; M = s_m[lt]; }
        S += __shfl_down(S, 2); C += __shfl_down(C, 2); M = fmaxf(M, __shfl_down(M, 2));
        S += __shfl_down(S, 1); C += __shfl_down(C, 1); M = fmaxf(M, __shfl_down(M, 1));

        unsigned ret = 0;
        if (lt == 0) {
            st(&ws[blockIdx.x],          S);
            st(&ws[NBLK + blockIdx.x],   C);
            st(&ws[2*NBLK + blockIdx.x], M);
            drain_vmem();                 // partials acked before L1 increment
            ret = bump(&wsu[3*NBLK + (g << 4)]);
        }
        ret = __shfl(ret, 0);             // in-wave broadcast, no barrier

        if ((ret & (GSIZE - 1)) == (GSIZE - 1)) {
            // group complete: signal L2 (no data to drain; ordered by the
            // control dependence on ret)
            unsigned r2 = 0;
            if (lt == 0) r2 = bump(&wsu[3584]);
            r2 = __shfl(r2, 0);

            if ((r2 & (GROUPS - 1)) == (GROUPS - 1)) {
                // all 1024 partials are at the coherence point: reduce them all
                float S2 = 0.f, C2 = 0.f, M2 = 0.f;
                #pragma unroll
                for (int j = 0; j < NBLK/64; ++j) {    // 16 x 3 independent loads
                    int b = lt + (j << 6);
                    S2 += ld(&ws[b]);
                    C2 += ld(&ws[NBLK + b]);
                    M2  = fmaxf(M2, ld(&ws[2*NBLK + b]));
                }
                #pragma unroll
                for (int o = 32; o > 0; o >>= 1) {
                    S2 += __shfl_down(S2, o);
                    C2 += __shfl_down(C2, o);
                    M2  = fmaxf(M2, __shfl_down(M2, o));
                }
                if (lt == 0) {
                    float li = (C2 > 0.f) ? W_IN * S2 / C2 : 0.f;
                    float nout = (float)NP - C2;
                    float lo = (nout > 0.f) ? W_OUT * M2 : 0.f;
                    out[0] = li + lo;
                }
            }
        }
    }
}

extern "C" void kernel_launch(void* const* d_in, const int* in_sizes, int n_in,
                              void* d_out, int out_size, void* d_ws, size_t ws_size,
                              hipStream_t stream) {
    const float* pts = (const float*)d_in[0];
    float* ws = (float*)d_ws;
    float* out = (float*)d_out;
    pbl_fused<<<NBLK, BLOCK, 0, stream>>>(pts, ws, out);
}

// Round 10
// 9.437 us; speedup vs baseline: 1.2323x; 1.0382x over previous
//
#include <hip/hip_runtime.h>

#define NP 1048576
#define BLOCK 256
#define PPT 8
#define NBLK (NP / (BLOCK * PPT))   /* 512 */
#define GROUPS 32
#define GSIZE (NBLK / GROUPS)       /* 16 */
#define W_IN 0.001f
#define W_OUT 1.0f
#define TOL 1e-8f
#define SQRT3 1.7320508f

// ws layout (float indices):
//   u64 packed (S,C) partials: u64[0..512)   == float[0..1024)
//   float M partials:          float[1024..1536)
//   L1 counters (32): u32 @ float-idx 1536 + 16*g   (64B apart, g = bid & 31)
//   L2 counter:       u32 @ float-idx 2112
// Protocol: relaxed agent-scope atomics only (coherence-point direct, no
// cache maintenance); producer ordering via s_waitcnt vmcnt(0) drains; the
// 16th finisher of a group bumps L2 (control-dependence ordering); the 32nd
// L2 bumper reduces all 512 partials directly. Counter tests are
// (ret & N-1)==N-1 -> correct for any initial (poisoned/leftover) value.

__device__ __forceinline__ void drain_vmem() {
    asm volatile("s_waitcnt vmcnt(0)" ::: "memory");
}
__device__ __forceinline__ void st64(unsigned long long* p, unsigned long long v) {
    __hip_atomic_store(p, v, __ATOMIC_RELAXED, __HIP_MEMORY_SCOPE_AGENT);
}
__device__ __forceinline__ unsigned long long ld64(const unsigned long long* p) {
    return __hip_atomic_load(p, __ATOMIC_RELAXED, __HIP_MEMORY_SCOPE_AGENT);
}
__device__ __forceinline__ void st32(float* p, float v) {
    __hip_atomic_store(p, v, __ATOMIC_RELAXED, __HIP_MEMORY_SCOPE_AGENT);
}
__device__ __forceinline__ float ld32(const float* p) {
    return __hip_atomic_load(p, __ATOMIC_RELAXED, __HIP_MEMORY_SCOPE_AGENT);
}
__device__ __forceinline__ unsigned bump(unsigned* p) {
    return __hip_atomic_fetch_add(p, 1u, __ATOMIC_RELAXED, __HIP_MEMORY_SCOPE_AGENT);
}

__global__ __launch_bounds__(BLOCK) void pbl_fused(
    const float* __restrict__ pts, float* __restrict__ ws, float* __restrict__ out)
{
    __shared__ float s_s[BLOCK/64], s_c[BLOCK/64], s_m[BLOCK/64];

    const int lt = threadIdx.x;
    const int tid = blockIdx.x * BLOCK + lt;
    const float4* p4 = (const float4*)pts;
    float4 f[6];
    #pragma unroll
    for (int k = 0; k < 6; ++k) f[k] = p4[tid*6 + k];
    float px[PPT] = {f[0].x, f[0].w, f[1].z, f[2].y, f[3].x, f[3].w, f[4].z, f[5].y};
    float py[PPT] = {f[0].y, f[1].x, f[1].w, f[2].z, f[3].y, f[4].x, f[4].w, f[5].z};
    float pz[PPT] = {f[0].z, f[1].y, f[2].x, f[2].w, f[3].z, f[4].y, f[5].x, f[5].w};

    float sum_in = 0.f, mx_out = 0.f;
    bool ins[PPT];
    #pragma unroll
    for (int i = 0; i < PPT; ++i) {
        float ux = fabsf(px[i]), uy = fabsf(py[i]), uz = fabsf(pz[i]);
        float s1 = ux + uy + uz;
        float hi = fmaxf(ux, fmaxf(uy, uz));
        float lo = fminf(ux, fminf(uy, uz));
        float mid = s1 - hi - lo;
        float ss = fmaf(px[i], px[i], fmaf(py[i], py[i], pz[i]*pz[i]));

        bool inside = (s1 - 1.f) <= TOL * SQRT3;           // max plane violation
        float d2v = fmaf(-2.f, hi, ss) + 1.f;              // min d2 to +-e_i vertices

        float t3 = (s1 - 1.f) * (1.f/3.f);                 // simplex projection
        float t2 = (hi + mid - 1.f) * 0.5f;
        float t1 = hi - 1.f;
        float d2_3 = 3.f * t3 * t3;
        float d2_2 = fmaf(lo, lo, 2.f * t2 * t2);
        float d2_1 = fmaf(t1, t1, fmaf(mid, mid, lo * lo));
        float sq = (lo > t3) ? d2_3 : ((mid > t2) ? d2_2 : d2_1);

        ins[i] = inside;
        sum_in += inside ? d2v : 0.f;
        mx_out  = inside ? mx_out : fmaxf(mx_out, sq);
    }

    // inside-count via ballot (scalar pipe)
    int wcnt = 0;
    #pragma unroll
    for (int i = 0; i < PPT; ++i)
        wcnt += __popcll(__ballot(ins[i]));

    // wave reduce sum & max
    #pragma unroll
    for (int o = 32; o > 0; o >>= 1) {
        sum_in += __shfl_down(sum_in, o);
        mx_out  = fmaxf(mx_out, __shfl_down(mx_out, o));
    }
    const int wave = lt >> 6;
    if ((lt & 63) == 0) { s_s[wave] = sum_in; s_c[wave] = (float)wcnt; s_m[wave] = mx_out; }
    __syncthreads();

    if (lt < 64) {                       // wave 0 runs the entire tail
        unsigned* wsu = (unsigned*)ws;
        unsigned long long* ws64 = (unsigned long long*)ws;
        const int g = blockIdx.x & (GROUPS - 1);

        float S = 0.f, C = 0.f, M = 0.f;
        if (lt < BLOCK/64) { S = s_s[lt]; C = s_c[lt]; M = s_m[lt]; }
        S += __shfl_down(S, 2); C += __shfl_down(C, 2); M = fmaxf(M, __shfl_down(M, 2));
        S += __shfl_down(S, 1); C += __shfl_down(C, 1); M = fmaxf(M, __shfl_down(M, 1));

        unsigned ret = 0;
        if (lt == 0) {
            unsigned long long sc = ((unsigned long long)__float_as_uint(C) << 32)
                                   | (unsigned long long)__float_as_uint(S);
            st64(&ws64[blockIdx.x], sc);
            st32(&ws[1024 + blockIdx.x], M);
            drain_vmem();                 // both partials acked before L1 bump
            ret = bump(&wsu[1536 + (g << 4)]);
        }
        ret = __shfl(ret, 0);             // in-wave broadcast, no barrier

        if ((ret & (GSIZE - 1)) == (GSIZE - 1)) {
            // group complete: signal L2 (no data produced => no drain needed)
            unsigned r2 = 0;
            if (lt == 0) r2 = bump(&wsu[2112]);
            r2 = __shfl(r2, 0);

            if ((r2 & (GROUPS - 1)) == (GROUPS - 1)) {
                // all 512 partials are at the coherence point: reduce them all
                float S2 = 0.f, C2 = 0.f, M2 = 0.f;
                #pragma unroll
                for (int j = 0; j < NBLK/64; ++j) {    // 8 x (u64 + f32) loads
                    int b = lt + (j << 6);
                    unsigned long long sc = ld64(&ws64[b]);
                    S2 += __uint_as_float((unsigned)(sc & 0xffffffffull));
                    C2 += __uint_as_float((unsigned)(sc >> 32));
                    M2  = fmaxf(M2, ld32(&ws[1024 + b]));
                }
                #pragma unroll
                for (int o = 32; o > 0; o >>= 1) {
                    S2 += __shfl_down(S2, o);
                    C2 += __shfl_down(C2, o);
                    M2  = fmaxf(M2, __shfl_down(M2, o));
                }
                if (lt == 0) {
                    float li = (C2 > 0.f) ? W_IN * S2 / C2 : 0.f;
                    float nout = (float)NP - C2;
                    float lo = (nout > 0.f) ? W_OUT * M2 : 0.f;
                    out[0] = li + lo;
                }
            }
        }
    }
}

extern "C" void kernel_launch(void* const* d_in, const int* in_sizes, int n_in,
                              void* d_out, int out_size, void* d_ws, size_t ws_size,
                              hipStream_t stream) {
    const float* pts = (const float*)d_in[0];
    float* ws = (float*)d_ws;
    float* out = (float*)d_out;
    pbl_fused<<<NBLK, BLOCK, 0, stream>>>(pts, ws, out);
}